// Round 1
// baseline (381.086 us; speedup 1.0000x reference)
//
#include <hip/hip_runtime.h>
#include <stdint.h>
#include <stddef.h>

#define NB 2
#define NT 4096
#define NC 768
#define NH 12
#define ND 64

typedef unsigned short u16;
typedef __attribute__((ext_vector_type(4))) float f32x4;
typedef __attribute__((ext_vector_type(16))) float f32x16;
typedef __attribute__((ext_vector_type(8))) unsigned short u16x8;
typedef __attribute__((ext_vector_type(4))) unsigned short u16x4;
typedef __attribute__((ext_vector_type(8))) __bf16 bf16x8;
typedef __attribute__((ext_vector_type(4))) unsigned int u32x4;

__device__ __forceinline__ u16 f2bf(float f) {
  uint32_t u = __builtin_bit_cast(uint32_t, f);
  u += 0x7FFFu + ((u >> 16) & 1u);   // RTNE
  return (u16)(u >> 16);
}
__device__ __forceinline__ bf16x8 asbf(u16x8 v) { return __builtin_bit_cast(bf16x8, v); }

// pack two f32 -> two bf16, round-half-up: 3 VALU
__device__ __forceinline__ uint32_t pkbf(float a, float b) {
  uint32_t ua = __builtin_bit_cast(uint32_t, a) + 0x8000u;
  uint32_t ub = __builtin_bit_cast(uint32_t, b) + 0x8000u;
  return __builtin_amdgcn_perm(ub, ua, 0x07060302u);
}
// truncating pack (P only; numerator/denominator stay consistent): 1 VALU
__device__ __forceinline__ uint32_t pktr(float a, float b) {
  return __builtin_amdgcn_perm(__builtin_bit_cast(uint32_t, b),
                               __builtin_bit_cast(uint32_t, a), 0x07060302u);
}

// ---------------- cast fp32 -> bf16 ----------------
__global__ void k_cast(const float* __restrict__ in, u16* __restrict__ out, int n4) {
  int i = blockIdx.x * blockDim.x + threadIdx.x;
  if (i < n4) {
    f32x4 v = ((const f32x4*)in)[i];
    u16x4 o;
    o[0] = f2bf(v[0]); o[1] = f2bf(v[1]); o[2] = f2bf(v[2]); o[3] = f2bf(v[3]);
    ((u16x4*)out)[i] = o;
  }
}

// -------- transpose + cast --------
__global__ void k_transpose(const float* __restrict__ in, u16* __restrict__ out,
                            int R, int Cn) {
  __shared__ float tile[32][33];
  int c0 = blockIdx.x * 32, r0 = blockIdx.y * 32;
  int tx = threadIdx.x & 31, ty = threadIdx.x >> 5;
  for (int i = ty; i < 32; i += 8)
    tile[i][tx] = in[(size_t)(r0 + i) * Cn + c0 + tx];
  __syncthreads();
  for (int i = ty; i < 32; i += 8)
    out[(size_t)(c0 + i) * R + r0 + tx] = f2bf(tile[tx][i]);
}

// -------- GEMM: C[M,N] = A[M,K] * Bt[N,K]^T --------
template <int EPI>
__global__ __launch_bounds__(256, 2)
void k_gemm_bt(const u16* __restrict__ A, const u16* __restrict__ Bt,
               int M, int N, int K,
               u16* __restrict__ o0, u16* __restrict__ o1, u16* __restrict__ o2,
               float* __restrict__ of) {
  __shared__ u16 As[128 * 40];
  __shared__ u16 Bs[128 * 40];
  const int tid = threadIdx.x;
  const int wave = tid >> 6, lane = tid & 63, quad = lane >> 4, lc = lane & 15;
  const int wm = (wave & 1) * 64, wn = (wave >> 1) * 64;
  const int bm = blockIdx.y * 128, bn = blockIdx.x * 128;

  const int sr = tid >> 2;
  const int sc8 = (tid & 3) * 8;
  const u16* ap0 = A + (size_t)(bm + sr) * K + sc8;
  const u16* ap1 = A + (size_t)(bm + 64 + sr) * K + sc8;
  const u16* bp0 = Bt + (size_t)(bn + sr) * K + sc8;
  const u16* bp1 = Bt + (size_t)(bn + 64 + sr) * K + sc8;
  u16* asl0 = &As[sr * 40 + sc8];
  u16* asl1 = &As[(64 + sr) * 40 + sc8];
  u16* bsl0 = &Bs[sr * 40 + sc8];
  u16* bsl1 = &Bs[(64 + sr) * 40 + sc8];

  f32x4 zv = {0.f, 0.f, 0.f, 0.f};
  f32x4 acc[4][4];
#pragma unroll
  for (int i = 0; i < 4; ++i)
#pragma unroll
    for (int j = 0; j < 4; ++j) acc[i][j] = zv;

  for (int k0 = 0; k0 < K; k0 += 32) {
    u16x8 a0 = *(const u16x8*)(ap0 + k0);
    u16x8 a1 = *(const u16x8*)(ap1 + k0);
    u16x8 b0 = *(const u16x8*)(bp0 + k0);
    u16x8 b1 = *(const u16x8*)(bp1 + k0);
    __syncthreads();
    *(u16x8*)asl0 = a0;
    *(u16x8*)asl1 = a1;
    *(u16x8*)bsl0 = b0;
    *(u16x8*)bsl1 = b1;
    __syncthreads();

    bf16x8 af[4], bfv[4];
#pragma unroll
    for (int mi = 0; mi < 4; ++mi)
      af[mi] = asbf(*(const u16x8*)&As[(wm + mi * 16 + lc) * 40 + quad * 8]);
#pragma unroll
    for (int ni = 0; ni < 4; ++ni)
      bfv[ni] = asbf(*(const u16x8*)&Bs[(wn + ni * 16 + lc) * 40 + quad * 8]);
#pragma unroll
    for (int mi = 0; mi < 4; ++mi)
#pragma unroll
      for (int ni = 0; ni < 4; ++ni)
        acc[mi][ni] = __builtin_amdgcn_mfma_f32_16x16x32_bf16(af[mi], bfv[ni],
                                                              acc[mi][ni], 0, 0, 0);
  }

  const int mrow0 = bm + wm + quad * 4;
#pragma unroll
  for (int mi = 0; mi < 4; ++mi) {
    const int mbase = mrow0 + mi * 16;
#pragma unroll
    for (int ni = 0; ni < 4; ++ni) {
      const int n = bn + wn + ni * 16 + lc;
      if (EPI == 0) {
#pragma unroll
        for (int r = 0; r < 4; ++r)
          of[(size_t)(mbase + r) * N + n] = acc[mi][ni][r];
      } else {
        const int sect = n / NC;          // 0=q 1=k 2=v
        const int wn2 = n - sect * NC;
        const int h = wn2 >> 6, d = wn2 & 63;
        const int b = mbase >> 12;
        const int t = mbase & (NT - 1);
        const float sc = (sect == 0) ? 0.18033688011112042f : 1.0f;  // log2e/8
        if (sect == 2) {
          u16x4 pk;
#pragma unroll
          for (int r = 0; r < 4; ++r) pk[r] = f2bf(acc[mi][ni][r]);
          *(u16x4*)&o2[((size_t)(b * NH + h) * ND + d) * NT + t] = pk;
        } else {
          u16* dst = (sect == 0) ? o0 : o1;
#pragma unroll
          for (int r = 0; r < 4; ++r)
            dst[((size_t)(b * NH + h) * NT + (t + r)) * ND + d] =
                f2bf(acc[mi][ni][r] * sc);
        }
      }
    }
  }
}

// ================= flash attention, causal, 32x32x16 MFMA =================
// 2-wave blocks, 768 blocks (24 bh x 32 pairs) = exactly 3 blocks/CU.
// Block owns dual Q-tiles qiA=pair, qiB=63-pair (64 rows each); each wave owns
// 32 q of A + 32 q of B, fused as one MFMA pass sharing K/V fragments (2 MFMAs
// per 16B fragment read -> 64 FLOP/LDS-byte, 2x the 16x16 structure).
// P never touches LDS: S^T lives per-lane (col = lane&31), repacked to the PV
// B-operand with pktr + v_permlane32_swap. Denominator l = in-lane sum of
// TRUNCATED exp values (consistent with bf16 P) + one shfl_xor(32) at the end.
// LDS: K,V tiles only, 16KB, XOR-swizzled (granule ^= row&7) -> conflict-free
// b128 reads/writes. All blocks walk t=0,1,2,... in lockstep for L2 reuse.

// exp+truncate+pack one 32x32 S tile -> 4 PV B-fragments (t = kt*16 slices)
__device__ __forceinline__ void softpack(const f32x16& s0, const f32x16& s1,
                                         int t0, int qg, bool msk, int l5,
                                         float& sl, bf16x8* pf) {
  uint32_t wv[16];
#pragma unroll
  for (int mt = 0; mt < 2; ++mt) {
    const f32x16& sv = mt ? s1 : s0;
    const int tb = t0 + mt * 32 + l5 * 4;
    float e[16];
#pragma unroll
    for (int r = 0; r < 16; ++r) {
      float v = sv[r];
      if (msk) {
        int tg = tb + (r & 3) + 8 * (r >> 2);
        v = (tg > qg) ? -1e30f : v;
      }
      e[r] = exp2f(v);
      sl += __builtin_bit_cast(float,
            __builtin_bit_cast(uint32_t, e[r]) & 0xFFFF0000u);
    }
#pragma unroll
    for (int i = 0; i < 8; ++i) wv[mt * 8 + i] = pktr(e[2 * i], e[2 * i + 1]);
  }
  // kt-th fragment: lane holds t = kt*16 + (lane>>5)*8 + j. The needed
  // half-exchange (lane <-> lane+32) is exactly permlane32_swap:
  //   swap(w[4k],w[4k+2]) -> frag words 0,2 ; swap(w[4k+1],w[4k+3]) -> 1,3.
#pragma unroll
  for (int kt = 0; kt < 4; ++kt) {
    uint32_t a = wv[kt * 4 + 0], b = wv[kt * 4 + 1];
    uint32_t c = wv[kt * 4 + 2], d = wv[kt * 4 + 3];
    auto r0 = __builtin_amdgcn_permlane32_swap(a, c, false, false);
    auto r1 = __builtin_amdgcn_permlane32_swap(b, d, false, false);
    u32x4 f = {r0[0], r1[0], r0[1], r1[1]};
    pf[kt] = __builtin_bit_cast(bf16x8, f);
  }
}

__global__ __launch_bounds__(128, 2)
void k_attn(const u16* __restrict__ Q, const u16* __restrict__ K,
            const u16* __restrict__ Vt, u16* __restrict__ Y) {
  __shared__ u16 SM[2][64 * 64];   // [0]=K tile [t][d], [1]=V^T tile [d][t]
  const int tid = threadIdx.x;
  const int lane = tid & 63, wave = tid >> 6;
  const int l5 = lane >> 5, l31 = lane & 31;
  const int bh = blockIdx.x >> 5, pair = blockIdx.x & 31;
  const int b = bh / NH, h = bh - b * NH;
  const u16* __restrict__ Qb = Q + (size_t)bh * NT * ND;
  const u16* __restrict__ Kb = K + (size_t)bh * NT * ND;
  const u16* __restrict__ Vb = Vt + (size_t)bh * (size_t)ND * NT;

  const int qwA = pair * 64 + wave * 32;
  const int qwB = (63 - pair) * 64 + wave * 32;
  const int qgA = qwA + l31, qgB = qwB + l31;
  const int ntiles = 64 - pair;

  // Q as B-operand frags: col q = l31, k(d) = ks*16 + l5*8 + j  (log2e/8 folded)
  bf16x8 bqA[4], bqB[4];
#pragma unroll
  for (int ks = 0; ks < 4; ++ks) {
    bqA[ks] = asbf(*(const u16x8*)(Qb + (size_t)(qwA + l31) * ND + ks * 16 + l5 * 8));
    bqB[ks] = asbf(*(const u16x8*)(Qb + (size_t)(qwB + l31) * ND + ks * 16 + l5 * 8));
  }

  f32x16 Zv;
#pragma unroll
  for (int i = 0; i < 16; ++i) Zv[i] = 0.f;
  f32x16 oA0 = Zv, oA1 = Zv, oB0 = Zv, oB1 = Zv;   // O^T, d-halves
  float slA = 0.f, slB = 0.f;                       // truncation-consistent l

  // staging: thread -> (row = c*16 + tid>>3, granule tid&7), dest XOR-swizzled
  const int srow = tid >> 3, sg = tid & 7;
  const int soff = srow * 64 + (sg ^ (srow & 7)) * 8;
  const u16* __restrict__ pKs = Kb + (size_t)srow * ND + sg * 8;
  const u16* __restrict__ pVs = Vb + (size_t)srow * NT + sg * 8;

  // frag read offsets (elements): row = l31 (+32 via imm), swizzled granule
  int fro[4];
#pragma unroll
  for (int ks = 0; ks < 4; ++ks)
    fro[ks] = l31 * 64 + (((ks * 2 + l5) ^ (l31 & 7)) * 8);

  // prefetch tile 0
  u16x8 st[8];
#pragma unroll
  for (int c = 0; c < 4; ++c) st[c] = *(const u16x8*)(pKs + (size_t)(c * 16) * ND);
#pragma unroll
  for (int c = 0; c < 4; ++c) st[4 + c] = *(const u16x8*)(pVs + (size_t)(c * 16) * NT);

#pragma unroll 1
  for (int tau = 0; tau < ntiles; ++tau) {
    const int t0 = tau * 64;
    __syncthreads();
#pragma unroll
    for (int c = 0; c < 4; ++c) {
      *(u16x8*)&SM[0][c * 1024 + soff] = st[c];
      *(u16x8*)&SM[1][c * 1024 + soff] = st[4 + c];
    }
    __syncthreads();

    const bool actA = (tau <= pair);   // block-uniform

    // ---- S^T = K Q^T : A = K frag (rows t), B = Q; mt = t-half ----
    f32x16 sA0 = Zv, sA1 = Zv, sB0 = Zv, sB1 = Zv;
#pragma unroll
    for (int ks = 0; ks < 4; ++ks) {
      bf16x8 k0 = asbf(*(const u16x8*)&SM[0][fro[ks]]);
      bf16x8 k1 = asbf(*(const u16x8*)&SM[0][2048 + fro[ks]]);
      if (actA) {
        sA0 = __builtin_amdgcn_mfma_f32_32x32x16_bf16(k0, bqA[ks], sA0, 0, 0, 0);
        sA1 = __builtin_amdgcn_mfma_f32_32x32x16_bf16(k1, bqA[ks], sA1, 0, 0, 0);
      }
      sB0 = __builtin_amdgcn_mfma_f32_32x32x16_bf16(k0, bqB[ks], sB0, 0, 0, 0);
      sB1 = __builtin_amdgcn_mfma_f32_32x32x16_bf16(k1, bqB[ks], sB1, 0, 0, 0);
    }

    // ---- softmax numerators, packed in-register (no LDS) ----
    bf16x8 pA[4], pB[4];
    if (actA) softpack(sA0, sA1, t0, qgA, tau == pair, l5, slA, pA);
    softpack(sB0, sB1, t0, qgB, tau == ntiles - 1, l5, slB, pB);

    // prefetch next tile (issued here so HBM latency hides under PV)
    if (tau + 1 < ntiles) {
      const int tn = t0 + 64;
#pragma unroll
      for (int c = 0; c < 4; ++c)
        st[c] = *(const u16x8*)(pKs + (size_t)(tn + c * 16) * ND);
#pragma unroll
      for (int c = 0; c < 4; ++c)
        st[4 + c] = *(const u16x8*)(pVs + (size_t)(c * 16) * NT + tn);
    }

    // ---- O^T += V^T P^T : A = V^T frag (rows d), B = packed P ----
#pragma unroll
    for (int kt = 0; kt < 4; ++kt) {
      bf16x8 v0 = asbf(*(const u16x8*)&SM[1][fro[kt]]);
      bf16x8 v1 = asbf(*(const u16x8*)&SM[1][2048 + fro[kt]]);
      if (actA) {
        oA0 = __builtin_amdgcn_mfma_f32_32x32x16_bf16(v0, pA[kt], oA0, 0, 0, 0);
        oA1 = __builtin_amdgcn_mfma_f32_32x32x16_bf16(v1, pA[kt], oA1, 0, 0, 0);
      }
      oB0 = __builtin_amdgcn_mfma_f32_32x32x16_bf16(v0, pB[kt], oB0, 0, 0, 0);
      oB1 = __builtin_amdgcn_mfma_f32_32x32x16_bf16(v1, pB[kt], oB1, 0, 0, 0);
    }
  }

  // ---- epilogue: combine lane-halves of l, normalize, write Y ----
  float lA = slA + __shfl_xor(slA, 32);
  float lB = slB + __shfl_xor(slB, 32);
  float invA = 1.f / lA, invB = 1.f / lB;
#pragma unroll
  for (int ph = 0; ph < 2; ++ph) {
    const f32x16& o0 = ph ? oB0 : oA0;
    const f32x16& o1 = ph ? oB1 : oA1;
    const float inv = ph ? invB : invA;
    const int qg = ph ? qgB : qgA;
    u16* yrow = Y + (size_t)(b * NT + qg) * NC + h * 64;
#pragma unroll
    for (int dt = 0; dt < 2; ++dt) {
      const f32x16& o = dt ? o1 : o0;
#pragma unroll
      for (int rq = 0; rq < 4; ++rq) {
        const int d = dt * 32 + 8 * rq + 4 * l5;
        uint2 w;
        w.x = pkbf(o[rq * 4 + 0] * inv, o[rq * 4 + 1] * inv);
        w.y = pkbf(o[rq * 4 + 2] * inv, o[rq * 4 + 3] * inv);
        *(uint2*)&yrow[d] = w;
      }
    }
  }
}

extern "C" void kernel_launch(void* const* d_in, const int* in_sizes, int n_in,
                              void* d_out, int out_size, void* d_ws, size_t ws_size,
                              hipStream_t stream) {
  (void)in_sizes; (void)n_in; (void)out_size; (void)ws_size;
  const float* x = (const float*)d_in[0];
  const float* w_qkv = (const float*)d_in[1];
  const float* w_out = (const float*)d_in[2];
  float* out = (float*)d_out;

  u16* ws = (u16*)d_ws;
  const size_t XE = (size_t)NB * NT * NC;       // 6291456 elements
  u16* xb  = ws;
  u16* wqT = xb + XE;
  u16* woT = wqT + (size_t)3 * NC * NC;
  u16* Qb  = woT + (size_t)NC * NC;
  u16* Kb  = Qb + XE;
  u16* Vtb = Kb + XE;
  u16* yb  = Vtb + XE;

  k_cast<<<(int)(XE / 4 / 256), 256, 0, stream>>>(x, xb, (int)(XE / 4));
  k_transpose<<<dim3(3 * NC / 32, NC / 32), 256, 0, stream>>>(w_qkv, wqT, NC, 3 * NC);
  k_transpose<<<dim3(NC / 32, NC / 32), 256, 0, stream>>>(w_out, woT, NC, NC);
  k_gemm_bt<1><<<dim3(3 * NC / 128, NB * NT / 128), 256, 0, stream>>>(
      xb, wqT, NB * NT, 3 * NC, NC, Qb, Kb, Vtb, nullptr);
  k_attn<<<dim3(32 * NB * NH), 128, 0, stream>>>(Qb, Kb, Vtb, yb);
  k_gemm_bt<0><<<dim3(NC / 128, NB * NT / 128), 256, 0, stream>>>(
      yb, woT, NB * NT, NC, NC, nullptr, nullptr, nullptr, out);
}

// Round 2
// 246.819 us; speedup vs baseline: 1.5440x; 1.5440x over previous
//
#include <hip/hip_runtime.h>
#include <stdint.h>
#include <stddef.h>

#define NB 2
#define NT 4096
#define NC 768
#define NH 12
#define ND 64

typedef unsigned short u16;
typedef __attribute__((ext_vector_type(4))) float f32x4;
typedef __attribute__((ext_vector_type(16))) float f32x16;
typedef __attribute__((ext_vector_type(8))) unsigned short u16x8;
typedef __attribute__((ext_vector_type(4))) unsigned short u16x4;
typedef __attribute__((ext_vector_type(8))) __bf16 bf16x8;
typedef __attribute__((ext_vector_type(4))) unsigned int u32x4;

__device__ __forceinline__ u16 f2bf(float f) {
  uint32_t u = __builtin_bit_cast(uint32_t, f);
  u += 0x7FFFu + ((u >> 16) & 1u);   // RTNE
  return (u16)(u >> 16);
}
__device__ __forceinline__ bf16x8 asbf(u16x8 v) { return __builtin_bit_cast(bf16x8, v); }

// pack two f32 -> two bf16, round-half-up: 3 VALU
__device__ __forceinline__ uint32_t pkbf(float a, float b) {
  uint32_t ua = __builtin_bit_cast(uint32_t, a) + 0x8000u;
  uint32_t ub = __builtin_bit_cast(uint32_t, b) + 0x8000u;
  return __builtin_amdgcn_perm(ub, ua, 0x07060302u);
}
// truncating pack (P only; numerator/denominator stay consistent): 1 VALU
__device__ __forceinline__ uint32_t pktr(float a, float b) {
  return __builtin_amdgcn_perm(__builtin_bit_cast(uint32_t, b),
                               __builtin_bit_cast(uint32_t, a), 0x07060302u);
}

// ---------------- cast fp32 -> bf16 ----------------
__global__ void k_cast(const float* __restrict__ in, u16* __restrict__ out, int n4) {
  int i = blockIdx.x * blockDim.x + threadIdx.x;
  if (i < n4) {
    f32x4 v = ((const f32x4*)in)[i];
    u16x4 o;
    o[0] = f2bf(v[0]); o[1] = f2bf(v[1]); o[2] = f2bf(v[2]); o[3] = f2bf(v[3]);
    ((u16x4*)out)[i] = o;
  }
}

// -------- transpose + cast --------
__global__ void k_transpose(const float* __restrict__ in, u16* __restrict__ out,
                            int R, int Cn) {
  __shared__ float tile[32][33];
  int c0 = blockIdx.x * 32, r0 = blockIdx.y * 32;
  int tx = threadIdx.x & 31, ty = threadIdx.x >> 5;
  for (int i = ty; i < 32; i += 8)
    tile[i][tx] = in[(size_t)(r0 + i) * Cn + c0 + tx];
  __syncthreads();
  for (int i = ty; i < 32; i += 8)
    out[(size_t)(c0 + i) * R + r0 + tx] = f2bf(tile[tx][i]);
}

// -------- GEMM: C[M,N] = A[M,K] * Bt[N,K]^T --------
template <int EPI>
__global__ __launch_bounds__(256, 2)
void k_gemm_bt(const u16* __restrict__ A, const u16* __restrict__ Bt,
               int M, int N, int K,
               u16* __restrict__ o0, u16* __restrict__ o1, u16* __restrict__ o2,
               float* __restrict__ of) {
  __shared__ u16 As[128 * 40];
  __shared__ u16 Bs[128 * 40];
  const int tid = threadIdx.x;
  const int wave = tid >> 6, lane = tid & 63, quad = lane >> 4, lc = lane & 15;
  const int wm = (wave & 1) * 64, wn = (wave >> 1) * 64;
  const int bm = blockIdx.y * 128, bn = blockIdx.x * 128;

  const int sr = tid >> 2;
  const int sc8 = (tid & 3) * 8;
  const u16* ap0 = A + (size_t)(bm + sr) * K + sc8;
  const u16* ap1 = A + (size_t)(bm + 64 + sr) * K + sc8;
  const u16* bp0 = Bt + (size_t)(bn + sr) * K + sc8;
  const u16* bp1 = Bt + (size_t)(bn + 64 + sr) * K + sc8;
  u16* asl0 = &As[sr * 40 + sc8];
  u16* asl1 = &As[(64 + sr) * 40 + sc8];
  u16* bsl0 = &Bs[sr * 40 + sc8];
  u16* bsl1 = &Bs[(64 + sr) * 40 + sc8];

  f32x4 zv = {0.f, 0.f, 0.f, 0.f};
  f32x4 acc[4][4];
#pragma unroll
  for (int i = 0; i < 4; ++i)
#pragma unroll
    for (int j = 0; j < 4; ++j) acc[i][j] = zv;

  for (int k0 = 0; k0 < K; k0 += 32) {
    u16x8 a0 = *(const u16x8*)(ap0 + k0);
    u16x8 a1 = *(const u16x8*)(ap1 + k0);
    u16x8 b0 = *(const u16x8*)(bp0 + k0);
    u16x8 b1 = *(const u16x8*)(bp1 + k0);
    __syncthreads();
    *(u16x8*)asl0 = a0;
    *(u16x8*)asl1 = a1;
    *(u16x8*)bsl0 = b0;
    *(u16x8*)bsl1 = b1;
    __syncthreads();

    bf16x8 af[4], bfv[4];
#pragma unroll
    for (int mi = 0; mi < 4; ++mi)
      af[mi] = asbf(*(const u16x8*)&As[(wm + mi * 16 + lc) * 40 + quad * 8]);
#pragma unroll
    for (int ni = 0; ni < 4; ++ni)
      bfv[ni] = asbf(*(const u16x8*)&Bs[(wn + ni * 16 + lc) * 40 + quad * 8]);
#pragma unroll
    for (int mi = 0; mi < 4; ++mi)
#pragma unroll
      for (int ni = 0; ni < 4; ++ni)
        acc[mi][ni] = __builtin_amdgcn_mfma_f32_16x16x32_bf16(af[mi], bfv[ni],
                                                              acc[mi][ni], 0, 0, 0);
  }

  const int mrow0 = bm + wm + quad * 4;
#pragma unroll
  for (int mi = 0; mi < 4; ++mi) {
    const int mbase = mrow0 + mi * 16;
#pragma unroll
    for (int ni = 0; ni < 4; ++ni) {
      const int n = bn + wn + ni * 16 + lc;
      if (EPI == 0) {
#pragma unroll
        for (int r = 0; r < 4; ++r)
          of[(size_t)(mbase + r) * N + n] = acc[mi][ni][r];
      } else {
        const int sect = n / NC;          // 0=q 1=k 2=v
        const int wn2 = n - sect * NC;
        const int h = wn2 >> 6, d = wn2 & 63;
        const int b = mbase >> 12;
        const int t = mbase & (NT - 1);
        const float sc = (sect == 0) ? 0.18033688011112042f : 1.0f;  // log2e/8
        if (sect == 2) {
          u16x4 pk;
#pragma unroll
          for (int r = 0; r < 4; ++r) pk[r] = f2bf(acc[mi][ni][r]);
          *(u16x4*)&o2[((size_t)(b * NH + h) * ND + d) * NT + t] = pk;
        } else {
          u16* dst = (sect == 0) ? o0 : o1;
#pragma unroll
          for (int r = 0; r < 4; ++r)
            dst[((size_t)(b * NH + h) * NT + (t + r)) * ND + d] =
                f2bf(acc[mi][ni][r] * sc);
        }
      }
    }
  }
}

// ============ flash attention v2: causal, 32x32x16, wave-split ============
// Grid = 24 bh x 64 q-tiles (descending qi: long blocks dispatch first).
// Block = 4 waves (qh = wave&1, th = wave>>1): each wave computes a 32q x 32t
// sub-tile per K/V tile.  No online rescale => t-tiles independent => th-pair
// waves hold partial O/l in registers and combine ONCE via LDS at epilogue.
// Per-wave live state ~120 VGPR (round-1's merged design needed ~220 -> spilled).
// P stays in registers: S^T cols are lane-local (32x32 C layout), repacked to
// the PV B-operand with pktr + permlane32_swap (proven in round 1).
// LDS: single 16KB K/V tile, XOR-swizzled (granule ^= row&7), reused as the
// epilogue park area.  Denominator = in-lane sum of TRUNCATED exp (consistent
// with bf16 P) + shfl_xor(32) + cross-wave add.
__device__ __forceinline__ void softpack16(const f32x16& s, int qrel, bool msk,
                                           int l5, float& sl, bf16x8* pf) {
  float e[16];
#pragma unroll
  for (int r = 0; r < 16; ++r) {
    float v = s[r];
    if (msk) {
      int tl = (r & 3) + 8 * (r >> 2) + 4 * l5;   // 32x32 C-layout row
      v = (tl > qrel) ? -1e30f : v;
    }
    e[r] = exp2f(v);
    sl += __builtin_bit_cast(float,
          __builtin_bit_cast(uint32_t, e[r]) & 0xFFFF0000u);
  }
  uint32_t wv[8];
#pragma unroll
  for (int i = 0; i < 8; ++i) wv[i] = pktr(e[2 * i], e[2 * i + 1]);
  // B-frag g covers t_local = g*16 + l5*8 + j; half-exchange = permlane32_swap
#pragma unroll
  for (int g = 0; g < 2; ++g) {
    auto r0 = __builtin_amdgcn_permlane32_swap(wv[g * 4 + 0], wv[g * 4 + 2], false, false);
    auto r1 = __builtin_amdgcn_permlane32_swap(wv[g * 4 + 1], wv[g * 4 + 3], false, false);
    u32x4 f = {r0[0], r1[0], r0[1], r1[1]};
    pf[g] = __builtin_bit_cast(bf16x8, f);
  }
}

__global__ __launch_bounds__(256, 3)
void k_attn(const u16* __restrict__ Q, const u16* __restrict__ K,
            const u16* __restrict__ Vt, u16* __restrict__ Y) {
  __shared__ u16 SM[2][64 * 64];   // [0]=K tile [t][d], [1]=V^T tile [d][t]
  __shared__ float PL[2][64];      // l park
  const int tid = threadIdx.x;
  const int lane = tid & 63, wave = tid >> 6;
  const int l5 = lane >> 5, l31 = lane & 31;
  const int qh = wave & 1, th = wave >> 1;
  const int bh = blockIdx.x % (NB * NH);
  const int qi = 63 - blockIdx.x / (NB * NH);      // long blocks first
  const int b = bh / NH, h = bh - b * NH;
  const u16* __restrict__ Qb = Q + (size_t)bh * NT * ND;
  const u16* __restrict__ Kb = K + (size_t)bh * NT * ND;
  const u16* __restrict__ Vb = Vt + (size_t)bh * (size_t)ND * NT;

  const int qg = qi * 64 + qh * 32 + l31;          // this lane's q column

  // Q as B-operand frags: col q = l31(+qh*32), k(d) = ks*16 + l5*8 + j
  bf16x8 bq[4];
#pragma unroll
  for (int ks = 0; ks < 4; ++ks)
    bq[ks] = asbf(*(const u16x8*)(Qb + (size_t)qg * ND + ks * 16 + l5 * 8));

  f32x16 Zv;
#pragma unroll
  for (int i = 0; i < 16; ++i) Zv[i] = 0.f;
  f32x16 o0 = Zv, o1 = Zv;     // O^T partial (d-halves), this wave's (qh,th)
  float sl = 0.f;              // truncation-consistent partial l

  // staging: 256 thr x 4 x 16B = 16KB/iter; dest XOR-swizzled
  const int srow = tid >> 3, sg = tid & 7;
  const int soff = srow * 64 + ((sg ^ (srow & 7)) * 8);
  const u16* __restrict__ pK = Kb + (size_t)srow * ND + sg * 8;
  const u16* __restrict__ pV = Vb + (size_t)srow * NT + sg * 8;

  // LDS frag offsets (elements), matching XOR swizzle
  int qfro[4];
#pragma unroll
  for (int ks = 0; ks < 4; ++ks)
    qfro[ks] = (th * 32 + l31) * 64 + (((ks * 2 + l5) ^ (l31 & 7)) * 8);
  int vfro[2];
#pragma unroll
  for (int kp = 0; kp < 2; ++kp)
    vfro[kp] = l31 * 64 + ((((2 * th + kp) * 2 + l5) ^ (l31 & 7)) * 8);

  // prefetch tile 0
  u16x8 st[4];
  st[0] = *(const u16x8*)(pK);
  st[1] = *(const u16x8*)(pK + (size_t)32 * ND);
  st[2] = *(const u16x8*)(pV);
  st[3] = *(const u16x8*)(pV + (size_t)32 * NT);

#pragma unroll 1
  for (int tau = 0; tau <= qi; ++tau) {
    __syncthreads();
    *(u16x8*)&SM[0][soff] = st[0];
    *(u16x8*)&SM[0][2048 + soff] = st[1];
    *(u16x8*)&SM[1][soff] = st[2];
    *(u16x8*)&SM[1][2048 + soff] = st[3];
    __syncthreads();

    const bool dg = (tau == qi);
    const bool act = !(dg && th > qh);    // wave-uniform
    bf16x8 p[2];
    if (act) {
      // S^T[32t x 32q] = K(th half) Q(qh)^T
      f32x16 s = Zv;
#pragma unroll
      for (int ks = 0; ks < 4; ++ks) {
        bf16x8 kf = asbf(*(const u16x8*)&SM[0][qfro[ks]]);
        s = __builtin_amdgcn_mfma_f32_32x32x16_bf16(kf, bq[ks], s, 0, 0, 0);
      }
      softpack16(s, l31, dg && (th == qh), l5, sl, p);
    }

    // prefetch next tile (all threads; hides HBM latency under PV)
    if (tau < qi) {
      const int tn = (tau + 1) * 64;
      st[0] = *(const u16x8*)(pK + (size_t)tn * ND);
      st[1] = *(const u16x8*)(pK + (size_t)(tn + 32) * ND);
      st[2] = *(const u16x8*)(pV + tn);
      st[3] = *(const u16x8*)(pV + (size_t)32 * NT + tn);
    }

    if (act) {
      // O^T += V^T(d-halves) P^T(this wave's t-slice)
#pragma unroll
      for (int kp = 0; kp < 2; ++kp) {
        bf16x8 v0 = asbf(*(const u16x8*)&SM[1][vfro[kp]]);
        bf16x8 v1 = asbf(*(const u16x8*)&SM[1][2048 + vfro[kp]]);
        o0 = __builtin_amdgcn_mfma_f32_32x32x16_bf16(v0, p[kp], o0, 0, 0, 0);
        o1 = __builtin_amdgcn_mfma_f32_32x32x16_bf16(v1, p[kp], o1, 0, 0, 0);
      }
    }
  }

  // ---- epilogue: combine l5 halves, then th-pair waves via LDS park ----
  float l = sl + __shfl_xor(sl, 32);
  __syncthreads();                       // done reading SM as K/V
  float* PK = (float*)&SM[0][0];         // 16KB park: [64 rows][64 lanes] f32
  if (th == 0) {
#pragma unroll
    for (int r = 0; r < 16; ++r) PK[(qh * 32 + r) * 64 + lane] = o0[r];
#pragma unroll
    for (int r = 0; r < 16; ++r) PK[(qh * 32 + 16 + r) * 64 + lane] = o1[r];
    PL[qh][lane] = l;
  }
  __syncthreads();
  if (th == 1) {
#pragma unroll
    for (int r = 0; r < 16; ++r) o0[r] += PK[(qh * 32 + r) * 64 + lane];
#pragma unroll
    for (int r = 0; r < 16; ++r) o1[r] += PK[(qh * 32 + 16 + r) * 64 + lane];
    l += PL[qh][lane];
    const float inv = 1.f / l;
    u16* yrow = Y + (size_t)(b * NT + qg) * NC + h * 64;
#pragma unroll
    for (int dh = 0; dh < 2; ++dh) {
      const f32x16& o = dh ? o1 : o0;
#pragma unroll
      for (int rq = 0; rq < 4; ++rq) {
        const int d = dh * 32 + 8 * rq + 4 * l5;
        uint2 w;
        w.x = pkbf(o[rq * 4 + 0] * inv, o[rq * 4 + 1] * inv);
        w.y = pkbf(o[rq * 4 + 2] * inv, o[rq * 4 + 3] * inv);
        *(uint2*)&yrow[d] = w;
      }
    }
  }
}

extern "C" void kernel_launch(void* const* d_in, const int* in_sizes, int n_in,
                              void* d_out, int out_size, void* d_ws, size_t ws_size,
                              hipStream_t stream) {
  (void)in_sizes; (void)n_in; (void)out_size; (void)ws_size;
  const float* x = (const float*)d_in[0];
  const float* w_qkv = (const float*)d_in[1];
  const float* w_out = (const float*)d_in[2];
  float* out = (float*)d_out;

  u16* ws = (u16*)d_ws;
  const size_t XE = (size_t)NB * NT * NC;       // 6291456 elements
  u16* xb  = ws;
  u16* wqT = xb + XE;
  u16* woT = wqT + (size_t)3 * NC * NC;
  u16* Qb  = woT + (size_t)NC * NC;
  u16* Kb  = Qb + XE;
  u16* Vtb = Kb + XE;
  u16* yb  = Vtb + XE;

  k_cast<<<(int)(XE / 4 / 256), 256, 0, stream>>>(x, xb, (int)(XE / 4));
  k_transpose<<<dim3(3 * NC / 32, NC / 32), 256, 0, stream>>>(w_qkv, wqT, NC, 3 * NC);
  k_transpose<<<dim3(NC / 32, NC / 32), 256, 0, stream>>>(w_out, woT, NC, NC);
  k_gemm_bt<1><<<dim3(3 * NC / 128, NB * NT / 128), 256, 0, stream>>>(
      xb, wqT, NB * NT, 3 * NC, NC, Qb, Kb, Vtb, nullptr);
  k_attn<<<dim3((NB * NH) * 64), 256, 0, stream>>>(Qb, Kb, Vtb, yb);
  k_gemm_bt<0><<<dim3(NC / 128, NB * NT / 128), 256, 0, stream>>>(
      yb, woT, NB * NT, NC, NC, nullptr, nullptr, nullptr, out);
}